// Round 7
// baseline (164.055 us; speedup 1.0000x reference)
//
#include <hip/hip_runtime.h>

// SSD300 post-process — FINAL build (kReps=1). R2 evidence: kernel < 55.6 us
// (below the harness's ~56 us poison fills in rocprof top-5); dur_us=163 is
// harness-dominated. Mandatory traffic ~139 MB -> ~25 us kernel floor.
//
// R6: fix compile error — __builtin_nontemporal_store needs a clang vector
// type, not HIP_vector_type<float,4>. Use ext_vector_type(4) for the 16B
// output store.
//
// R5 changes vs R1 (latency-shaped):
//  1. offsets/dboxes float4 loads issued BEFORE the LDS staging loop so their
//     HBM latency hides under the conf streaming (were serialized after the
//     barrier: dependent-load stall per wave).
//  2. nontemporal stores for all outputs (write-once streams; keep L2 for
//     the conf read stream).
//
// Layout (unchanged):
//  - block = 256 threads = 256 consecutive anchors of one batch image.
//  - conf chunk (256*21 f32 = 21.5 KB) staged to LDS via coalesced float4
//    (chunk base 16B-aligned: 256*21*4 and 8732*21*4 are multiples of 16).
//  - LDS read stride 21 floats (odd) -> 2 lanes/bank on wave64 = free (m136).
//  - 21.5 KB LDS -> 7 blocks/CU -> 28 waves/CU occupancy.
// Output flat f32: [boxes B*N*4][pred_cls B*N][valid B*N].

constexpr int kB    = 128;
constexpr int kNBox = 8732;
constexpr int kNCls = 21;
constexpr int kChunk = 256;
constexpr float kConfThresh = 0.05f;

typedef float f32x4 __attribute__((ext_vector_type(4)));

__global__ __launch_bounds__(kChunk) void ssd_decode_kernel(
    const float* __restrict__ offsets,   // [B, N, 4]
    const float* __restrict__ conf,      // [B, N, 21]
    const float* __restrict__ dboxes,    // [N, 4]
    float* __restrict__ out)             // [B*N*4 | B*N | B*N]
{
    __shared__ __align__(16) float s_conf[kChunk * kNCls];  // 21504 B

    const int b   = blockIdx.y;
    const int n0  = blockIdx.x * kChunk;
    const int cnt = min(kChunk, kNBox - n0);
    const int tid = threadIdx.x;

    // ---- prefetch per-anchor operands BEFORE the staging barrier ----
    // (clamped index keeps tail-block lanes in-bounds; stores stay guarded)
    const int n  = n0 + min(tid, cnt - 1);
    const size_t an = (size_t)b * kNBox + n;
    const f32x4 off = reinterpret_cast<const f32x4*>(offsets)[an];
    const f32x4 d   = reinterpret_cast<const f32x4*>(dboxes)[n];

    // ---- stage confidences chunk into LDS (coalesced float4) ----
    const size_t coff = ((size_t)b * kNBox + n0) * kNCls;
    const int nflt = cnt * kNCls;          // 5376 (full) or 588 (tail chunk)
    const int nv4  = nflt >> 2;            // both divisible by 4
    const f32x4* __restrict__ c4 = reinterpret_cast<const f32x4*>(conf + coff);
    f32x4* s4 = reinterpret_cast<f32x4*>(s_conf);
    for (int i = tid; i < nv4; i += kChunk) {
        s4[i] = c4[i];
    }
    for (int i = (nv4 << 2) + tid; i < nflt; i += kChunk) {  // generic tail; no-op here
        s_conf[i] = conf[coff + i];
    }
    __syncthreads();

    if (tid < cnt) {
        // ---- argmax over 21 classes (first-occurrence on ties) ----
        const float* c = s_conf + tid * kNCls;
        float best = c[0];
        int cls = 0;
        #pragma unroll
        for (int k = 1; k < kNCls; ++k) {
            const float v = c[k];
            if (v > best) { best = v; cls = k; }
        }
        const bool valid = (cls != 0) && (best > kConfThresh);

        // ---- box decode (operands already in registers) ----
        const float cx = d.x + off.x * d.z;
        const float cy = d.y + off.y * d.w;
        const float w  = d.z * expf(off.z);
        const float h  = d.w * expf(off.w);

        f32x4 box;
        if (valid) {
            box.x = cx - 0.5f * w;
            box.y = cy - 0.5f * h;
            box.z = cx + 0.5f * w;
            box.w = cy + 0.5f * h;
        } else {
            box = (f32x4)(0.0f);
        }
        __builtin_nontemporal_store(box, reinterpret_cast<f32x4*>(out) + an);
        __builtin_nontemporal_store((float)cls, out + (size_t)kB * kNBox * 4 + an);
        __builtin_nontemporal_store(valid ? 1.0f : 0.0f, out + (size_t)kB * kNBox * 5 + an);
    }
}

extern "C" void kernel_launch(void* const* d_in, const int* in_sizes, int n_in,
                              void* d_out, int out_size, void* d_ws, size_t ws_size,
                              hipStream_t stream) {
    const float* offsets = (const float*)d_in[0];
    const float* conf    = (const float*)d_in[1];
    const float* dboxes  = (const float*)d_in[2];
    float* out = (float*)d_out;

    dim3 grid((kNBox + kChunk - 1) / kChunk, kB);  // 35 x 128 = 4480 blocks
    ssd_decode_kernel<<<grid, kChunk, 0, stream>>>(offsets, conf, dboxes, out);
}